// Round 8
// baseline (47.603 us; speedup 1.0000x reference)
//
#include <hip/hip_runtime.h>
#include <hip/hip_bf16.h>

// LCN: B=512, C=1, H=W=280, K=S=28, F=10, SPAN=100 (10x10), DEC_IN=1000, OUT=10
#define HW      280
#define IMG     78400        // 280*280
#define KK      28
#define F_N     10
#define SPAN    100
#define OUT_N   10
#define P_PLANE 512000       // 1000*512

typedef short s16x8 __attribute__((ext_vector_type(8)));   // 8 bf16 (4 VGPRs)
typedef float f32x4 __attribute__((ext_vector_type(4)));   // MFMA C/D

// wprep: wbuf[s][r][f 16][k 32] bf16, zero-padded f>=10, k>=28.
// u32 slot idx = ((s*28+r)*16 + f)*16 + k2   (k2 = pair of k)
__global__ __launch_bounds__(256) void wprep(const float* __restrict__ cw,
                                             unsigned* __restrict__ wbuf) {
  const int idx = blockIdx.x * 256 + (int)threadIdx.x;  // 0..716799
  const int k2  = idx & 15;
  const int f   = (idx >> 4) & 15;
  const int rs  = idx >> 8;          // r + 28*s
  const int r   = rs % 28;
  const int s   = rs / 28;
  unsigned out = 0;
  if (f < F_N) {
    const int k0 = k2 * 2, k1 = k0 + 1;
    const float v0 = (k0 < KK) ? cw[(size_t)(f * SPAN + s) * (KK * KK) + r * KK + k0] : 0.f;
    const float v1 = (k1 < KK) ? cw[(size_t)(f * SPAN + s) * (KK * KK) + r * KK + k1] : 0.f;
    __hip_bfloat162 h2 = __float22bfloat162_rn(make_float2(v0, v1));
    out = *reinterpret_cast<unsigned*>(&h2);
  }
  wbuf[idx] = out;
}

// Conv via MFMA: grid 1280 = bg(32: 16 b) x hs(10) x rq(4: 7 rows).
// XCD swizzle keeps each (hs,rq) w-slice on one XCD (L2-hot wbuf).
// Per row: stage 16 b x 1120 B FULLY COALESCED -> bf16 -> swizzled LDS
// [b16][k320] (k padded to 32/ws, pads pre-zeroed); each wave owns 2-3 ws,
// per ws: 1 ds_read_b128 A-frag + 1 coalesced 16B/lane B-frag + 1 MFMA.
__global__ __launch_bounds__(256, 4) void lcn_conv(
    const float* __restrict__ x, const unsigned short* __restrict__ wbuf,
    float* __restrict__ P) {
  const int bid  = blockIdx.x;       // 0..1279
  const int xcd  = bid & 7;
  const int grp  = bid >> 3;         // 0..159
  const int hsrq = xcd + 8 * (grp % 5);  // 0..39, fixed per XCD set
  const int bg   = grp / 5;          // 0..31
  const int hs   = hsrq >> 2;
  const int rq   = hsrq & 3;

  const int tid  = (int)threadIdx.x;
  const int lane = tid & 63;
  const int wid  = tid >> 6;
  const int l15  = lane & 15;
  const int kg   = lane >> 4;        // 0..3

  __shared__ short xl[2][16 * 320];  // 20.5 KB double-buffered A-tile

  // zero the k-pad slots (k 28..31 of each ws), same swizzle as data
  for (int i = tid; i < 2 * 160; i += 256) {
    const int buf = i / 160, j = i - buf * 160;
    const int b = j / 10, ws = j - b * 10;
    const int sidx = (b * 320 + ws * 32 + 28) ^ ((b & 7) << 3);
    *reinterpret_cast<short4*>(&xl[buf][sidx]) = make_short4(0, 0, 0, 0);
  }

  const int nun = (wid < 2) ? 3 : 2;             // ws units per wave (3,3,2,2)
  const int wsl[3] = {wid, wid + 4, wid + 8};

  f32x4 acc[3];
#pragma unroll
  for (int u = 0; u < 3; ++u) acc[u] = (f32x4){0.f, 0.f, 0.f, 0.f};

  const int row0 = hs * KK + rq * 7;
  const float* xbase = x + (size_t)bg * 16 * IMG + (size_t)row0 * HW;

  float4 stg[5];
  auto issue = [&](int r) {                      // coalesced full-row loads
#pragma unroll
    for (int j = 0; j < 5; ++j) {
      const int i = tid + 256 * j;
      if (i < 1120) {
        const int b = i / 70, q = i - b * 70;
        stg[j] = *reinterpret_cast<const float4*>(
            xbase + (size_t)b * IMG + (size_t)r * HW + q * 4);
      }
    }
  };
  auto commit = [&](int buf) {                   // cvt + swizzled ds_write
#pragma unroll
    for (int j = 0; j < 5; ++j) {
      const int i = tid + 256 * j;
      if (i < 1120) {
        const int b = i / 70, q = i - b * 70;
        const int ws = q / 7, c4 = q - ws * 7;
        __hip_bfloat162 h0 = __float22bfloat162_rn(make_float2(stg[j].x, stg[j].y));
        __hip_bfloat162 h1 = __float22bfloat162_rn(make_float2(stg[j].z, stg[j].w));
        const int sidx = (b * 320 + ws * 32 + c4 * 4) ^ ((b & 7) << 3);
        uint2 pk;
        pk.x = *reinterpret_cast<unsigned*>(&h0);
        pk.y = *reinterpret_cast<unsigned*>(&h1);
        *reinterpret_cast<uint2*>(&xl[buf][sidx]) = pk;
      }
    }
  };

  issue(0);
  commit(0);
  __syncthreads();

  for (int r = 0; r < 7; ++r) {
    const int buf = r & 1;
    if (r < 6) issue(r + 1);                     // loads in flight under MFMA
    const int rr = rq * 7 + r;
#pragma unroll
    for (int u = 0; u < 3; ++u) {
      if (u < nun) {
        const int ws = wsl[u];
        const int s  = hs * 10 + ws;
        // B-frag: lane reads w[f=l15][k=kg*8..+7] -- 16B/lane, 1KB coalesced
        const s16x8 bfr = *reinterpret_cast<const s16x8*>(
            wbuf + (size_t)(s * 28 + rr) * 512 + l15 * 32 + kg * 8);
        // A-frag: lane reads x[b=l15][k=ws*32+kg*8..+7] from swizzled LDS
        const int sidx = (l15 * 320 + ws * 32 + kg * 8) ^ ((l15 & 7) << 3);
        const s16x8 afr = *reinterpret_cast<const s16x8*>(&xl[buf][sidx]);
        acc[u] = __builtin_amdgcn_mfma_f32_16x16x32_bf16(afr, bfr, acc[u], 0, 0, 0);
      }
    }
    if (r < 6) commit(buf ^ 1);
    __syncthreads();
  }

  // D layout: row(b-off) = kg*4+j, col(f) = l15. P[rq][f*100+s][b].
  if (l15 < F_N) {
#pragma unroll
    for (int u = 0; u < 3; ++u) {
      if (u < nun) {
        const int s = hs * 10 + wsl[u];
        float* Pp = P + (size_t)rq * P_PLANE + (size_t)(l15 * SPAN + s) * 512
                      + bg * 16 + kg * 4;
        *reinterpret_cast<float4*>(Pp) =
            make_float4(acc[u][0], acc[u][1], acc[u][2], acc[u][3]);
      }
    }
  }
}

// Combine 4 rq quarters + bias + relu + decoder partials. (unchanged)
__global__ __launch_bounds__(256) void lcn_dec(
    const float* __restrict__ P, const float* __restrict__ cb,
    const float* __restrict__ dw, float* __restrict__ yp) {
  const int bid    = blockIdx.x;
  const int dchunk = bid >> 3;     // 0..24
  const int bg     = bid & 7;
  const int lane   = threadIdx.x & 63;
  const int swid   = __builtin_amdgcn_readfirstlane((int)(threadIdx.x >> 6));
  const int d0     = dchunk * 40 + swid * 10;

  const float* Pb = P + (size_t)bg * 64 + lane;
  float acc[OUT_N];
#pragma unroll
  for (int o = 0; o < OUT_N; ++o) acc[o] = 0.f;

#pragma unroll
  for (int dd = 0; dd < 10; ++dd) {
    const int d = d0 + dd;                       // wave-uniform
    const float* pd = Pb + (size_t)d * 512;
    const float p = pd[0] + pd[P_PLANE] + pd[2 * (size_t)P_PLANE] + pd[3 * (size_t)P_PLANE];
    const float h = fmaxf(p + cb[d], 0.f);
#pragma unroll
    for (int o = 0; o < OUT_N; ++o)
      acc[o] = fmaf(h, dw[o * 1000 + d], acc[o]);
  }
  float* ypp = yp + (size_t)(dchunk * 4 + swid) * 5120 + bg * 64 + lane;
#pragma unroll
  for (int o = 0; o < OUT_N; ++o) ypp[(size_t)o * 512] = acc[o];
}

// y[b][o] = db[o] + sum over 100 yp planes (unchanged)
__global__ __launch_bounds__(256) void lcn_yred(
    const float* __restrict__ yp, const float* __restrict__ db,
    float* __restrict__ y) {
  const int idx = blockIdx.x * 256 + (int)threadIdx.x;  // 0..5119 = o*512+b
  const int o = idx >> 9;
  const int b = idx & 511;
  float a = db[o];
#pragma unroll 10
  for (int p = 0; p < 100; ++p) a += yp[(size_t)p * 5120 + idx];
  y[b * OUT_N + o] = a;
}

extern "C" void kernel_launch(void* const* d_in, const int* in_sizes, int n_in,
                              void* d_out, int out_size, void* d_ws, size_t ws_size,
                              hipStream_t stream) {
  const float* x  = (const float*)d_in[0];   // [512,1,280,280]
  const float* cw = (const float*)d_in[1];   // [1000,1,28,28]
  const float* cb = (const float*)d_in[2];   // [1000,1]
  const float* dw = (const float*)d_in[3];   // [10,1000]
  const float* db = (const float*)d_in[4];   // [10]
  float* y = (float*)d_out;                  // [512,10]

  float*    P    = (float*)d_ws;                       // [4][1000][512] = 8.192 MB
  float*    yp   = P + 4 * (size_t)P_PLANE;            // [100][10][512] = 2.048 MB
  unsigned* wbuf = (unsigned*)(yp + 100 * 5120);       // [100][28][16][16] u32 = 2.867 MB

  wprep   <<<dim3(2800), dim3(256), 0, stream>>>(cw, wbuf);
  lcn_conv<<<dim3(1280), dim3(256), 0, stream>>>(x, (const unsigned short*)wbuf, P);
  lcn_dec <<<dim3(200),  dim3(256), 0, stream>>>(P, cb, dw, yp);
  lcn_yred<<<dim3(20),   dim3(256), 0, stream>>>(yp, db, y);
}

// Round 9
// 45.328 us; speedup vs baseline: 1.0502x; 1.0502x over previous
//
#include <hip/hip_runtime.h>
#include <hip/hip_bf16.h>

// LCN: B=512, C=1, H=W=280, K=S=28, F=10, SPAN=100 (10x10), DEC_IN=1000, OUT=10
#define HW      280
#define IMG     78400        // 280*280
#define KK      28
#define F_N     10
#define SPAN    100
#define OUT_N   10
#define P_PLANE 512000       // 1000*512

typedef short s16x8 __attribute__((ext_vector_type(8)));   // 8 bf16 (4 VGPRs)
typedef float f32x4 __attribute__((ext_vector_type(4)));   // MFMA C/D

static __device__ __forceinline__ unsigned bits2(__hip_bfloat162 h) {
  return *reinterpret_cast<unsigned*>(&h);
}

// wprep: wbuf[s][r][f 16][k 32] bf16, zero-padded f>=10, k>=28.
// One uint4 (8 bf16) per thread: idx4 = ((s*28+r)*16+f)*4 + k8.
__global__ __launch_bounds__(256) void wprep(const float* __restrict__ cw,
                                             uint4* __restrict__ wbuf4) {
  const int idx = blockIdx.x * 256 + (int)threadIdx.x;  // 0..179199
  const int k8  = idx & 3;
  const int f   = (idx >> 2) & 15;
  const int rs  = idx >> 6;          // r + 28*s
  const int r   = rs % 28;
  const int s   = rs / 28;
  uint4 out = make_uint4(0, 0, 0, 0);
  if (f < F_N) {
    const float* base = cw + (size_t)(f * SPAN + s) * (KK * KK) + r * KK + k8 * 8;
    const float4 a = *reinterpret_cast<const float4*>(base);
    out.x = bits2(__float22bfloat162_rn(make_float2(a.x, a.y)));
    out.y = bits2(__float22bfloat162_rn(make_float2(a.z, a.w)));
    if (k8 < 3) {                    // k8==3 covers k 24..27 only (28..31 pad)
      const float4 c = *reinterpret_cast<const float4*>(base + 4);
      out.z = bits2(__float22bfloat162_rn(make_float2(c.x, c.y)));
      out.w = bits2(__float22bfloat162_rn(make_float2(c.z, c.w)));
    }
  }
  wbuf4[idx] = out;
}

// Conv via MFMA: grid 1280 = bg(32: 16 b) x hs(10) x rq(4: 7 rows).
// Staging: full 1120B rows coalesced -> bf16 -> swizzled double-buffered LDS.
// ROUND 9: depth-2 register prefetch (stgA/stgB; row r+2 issued while row r
// computes) -> ~2 iterations of HBM-latency cover at the barrier boundary.
__global__ __launch_bounds__(256, 4) void lcn_conv(
    const float* __restrict__ x, const unsigned short* __restrict__ wbuf,
    float* __restrict__ P) {
  const int bid  = blockIdx.x;       // 0..1279
  const int xcd  = bid & 7;
  const int grp  = bid >> 3;         // 0..159
  const int hsrq = xcd + 8 * (grp % 5);  // 0..39, fixed per XCD set
  const int bg   = grp / 5;          // 0..31
  const int hs   = hsrq >> 2;
  const int rq   = hsrq & 3;

  const int tid  = (int)threadIdx.x;
  const int lane = tid & 63;
  const int wid  = tid >> 6;
  const int l15  = lane & 15;
  const int kg   = lane >> 4;        // 0..3

  __shared__ short xl[2][16 * 320];  // 20.5 KB double-buffered A-tile

  // zero the k-pad slots (k 28..31 of each ws), same swizzle as data
  for (int i = tid; i < 2 * 160; i += 256) {
    const int buf = i / 160, j = i - buf * 160;
    const int b = j / 10, ws = j - b * 10;
    const int sidx = (b * 320 + ws * 32 + 28) ^ ((b & 7) << 3);
    *reinterpret_cast<short4*>(&xl[buf][sidx]) = make_short4(0, 0, 0, 0);
  }

  const int nun = (wid < 2) ? 3 : 2;             // ws units per wave (3,3,2,2)
  const int wsl[3] = {wid, wid + 4, wid + 8};

  f32x4 acc[3];
#pragma unroll
  for (int u = 0; u < 3; ++u) acc[u] = (f32x4){0.f, 0.f, 0.f, 0.f};

  const int row0 = hs * KK + rq * 7;
  const float* xbase = x + (size_t)bg * 16 * IMG + (size_t)row0 * HW;

  float4 stgA[5], stgB[5];

#define ISSUE(STG, R)                                                       \
  _Pragma("unroll")                                                         \
  for (int j = 0; j < 5; ++j) {                                             \
    const int i = tid + 256 * j;                                            \
    if (i < 1120) {                                                         \
      const int b = i / 70, q = i - b * 70;                                 \
      STG[j] = *reinterpret_cast<const float4*>(                            \
          xbase + (size_t)b * IMG + (size_t)(R) * HW + q * 4);              \
    }                                                                       \
  }

#define COMMIT(STG, BUF)                                                    \
  _Pragma("unroll")                                                         \
  for (int j = 0; j < 5; ++j) {                                             \
    const int i = tid + 256 * j;                                            \
    if (i < 1120) {                                                         \
      const int b = i / 70, q = i - b * 70;                                 \
      const int ws = q / 7, c4 = q - ws * 7;                                \
      const int sidx = (b * 320 + ws * 32 + c4 * 4) ^ ((b & 7) << 3);       \
      uint2 pk;                                                             \
      pk.x = bits2(__float22bfloat162_rn(make_float2(STG[j].x, STG[j].y))); \
      pk.y = bits2(__float22bfloat162_rn(make_float2(STG[j].z, STG[j].w))); \
      *reinterpret_cast<uint2*>(&xl[BUF][sidx]) = pk;                       \
    }                                                                       \
  }

  ISSUE(stgA, 0)               // row 0 -> slot A
  ISSUE(stgB, 1)               // row 1 -> slot B
  COMMIT(stgA, 0)
  __syncthreads();

#pragma unroll
  for (int r = 0; r < 7; ++r) {
    const int buf = r & 1;
    const int rr  = rq * 7 + r;
#pragma unroll
    for (int u = 0; u < 3; ++u) {
      if (u < nun) {
        const int ws = wsl[u];
        const int s  = hs * 10 + ws;
        // B-frag: lane reads w[f=l15][k=kg*8..+7] -- 16B/lane, 1KB coalesced
        const s16x8 bfr = *reinterpret_cast<const s16x8*>(
            wbuf + (size_t)(s * 28 + rr) * 512 + l15 * 32 + kg * 8);
        // A-frag: lane reads x[b=l15][k=ws*32+kg*8..+7] from swizzled LDS
        const int sidx = (l15 * 320 + ws * 32 + kg * 8) ^ ((l15 & 7) << 3);
        const s16x8 afr = *reinterpret_cast<const s16x8*>(&xl[buf][sidx]);
        acc[u] = __builtin_amdgcn_mfma_f32_16x16x32_bf16(afr, bfr, acc[u], 0, 0, 0);
      }
    }
    if (r < 6) {
      if (r & 1) { COMMIT(stgA, 0) } else { COMMIT(stgB, 1) }   // row r+1
    }
    if (r < 5) {
      if (r & 1) { ISSUE(stgB, r + 2) } else { ISSUE(stgA, r + 2) }
    }
    __syncthreads();
  }

  // D layout: row(b-off) = kg*4+j, col(f) = l15. P[rq][f*100+s][b].
  if (l15 < F_N) {
#pragma unroll
    for (int u = 0; u < 3; ++u) {
      if (u < nun) {
        const int s = hs * 10 + wsl[u];
        float* Pp = P + (size_t)rq * P_PLANE + (size_t)(l15 * SPAN + s) * 512
                      + bg * 16 + kg * 4;
        *reinterpret_cast<float4*>(Pp) =
            make_float4(acc[u][0], acc[u][1], acc[u][2], acc[u][3]);
      }
    }
  }
}

// Combine 4 rq quarters + bias + relu + decoder partials.
// grid 50 blocks x 512 threads; thread = b (fully coalesced P reads, no LDS,
// no cross-lane reduce); each block owns 20 d's. yp[50][10][512].
__global__ __launch_bounds__(512) void lcn_dec(
    const float* __restrict__ P, const float* __restrict__ cb,
    const float* __restrict__ dw, float* __restrict__ yp) {
  const int dchunk = blockIdx.x;        // 0..49
  const int b      = (int)threadIdx.x;  // 0..511

  const float* Pb = P + b;
  float acc[OUT_N];
#pragma unroll
  for (int o = 0; o < OUT_N; ++o) acc[o] = 0.f;

#pragma unroll
  for (int dd = 0; dd < 20; ++dd) {
    const int d = dchunk * 20 + dd;     // wave-uniform
    const float* pd = Pb + (size_t)d * 512;
    const float p = pd[0] + pd[P_PLANE] + pd[2 * (size_t)P_PLANE]
                          + pd[3 * (size_t)P_PLANE];
    const float h = fmaxf(p + cb[d], 0.f);
#pragma unroll
    for (int o = 0; o < OUT_N; ++o)
      acc[o] = fmaf(h, dw[o * 1000 + d], acc[o]);  // wave-uniform -> s_load
  }
#pragma unroll
  for (int o = 0; o < OUT_N; ++o)
    yp[(size_t)(dchunk * OUT_N + o) * 512 + b] = acc[o];
}

// y[b][o] = db[o] + sum over 50 yp planes; grid 40 x 128 (5120 outputs)
__global__ __launch_bounds__(128) void lcn_yred(
    const float* __restrict__ yp, const float* __restrict__ db,
    float* __restrict__ y) {
  const int idx = blockIdx.x * 128 + (int)threadIdx.x;  // 0..5119 = o*512+b
  const int o = idx >> 9;
  const int b = idx & 511;
  float a = db[o];
#pragma unroll 10
  for (int p = 0; p < 50; ++p) a += yp[(size_t)p * 5120 + idx];
  y[b * OUT_N + o] = a;
}

extern "C" void kernel_launch(void* const* d_in, const int* in_sizes, int n_in,
                              void* d_out, int out_size, void* d_ws, size_t ws_size,
                              hipStream_t stream) {
  const float* x  = (const float*)d_in[0];   // [512,1,280,280]
  const float* cw = (const float*)d_in[1];   // [1000,1,28,28]
  const float* cb = (const float*)d_in[2];   // [1000,1]
  const float* dw = (const float*)d_in[3];   // [10,1000]
  const float* db = (const float*)d_in[4];   // [10]
  float* y = (float*)d_out;                  // [512,10]

  float*    P    = (float*)d_ws;                       // [4][1000][512] = 8.192 MB
  float*    yp   = P + 4 * (size_t)P_PLANE;            // [50][10][512]  = 1.024 MB
  uint4*    wbuf = (uint4*)(yp + 50 * 5120);           // [100][28][16][16]u32 = 2.867 MB

  wprep   <<<dim3(700),  dim3(256), 0, stream>>>(cw, wbuf);
  lcn_conv<<<dim3(1280), dim3(256), 0, stream>>>(x, (const unsigned short*)wbuf, P);
  lcn_dec <<<dim3(50),   dim3(512), 0, stream>>>(P, cb, dw, yp);
  lcn_yred<<<dim3(40),   dim3(128), 0, stream>>>(yp, db, y);
}